// Round 1
// baseline (296.600 us; speedup 1.0000x reference)
//
#include <hip/hip_runtime.h>

// ---------------------------------------------------------------------------
// ModulatedConvBlock on MI355X (gfx950)
//   y   = prelu(conv3x3(upsample2x(x)*style, w)*demod + b + ns*noise); y=(y+t)/r2
//   out = clamp(conv1x1(y*OUT_SCALE, ow) + ob, 0, 1)
// Strategy: bf16 MFMA implicit GEMM (32x32x16), weights as direct global
// fragments, xm staged in LDS with XOR bank swizzle, fused epilogue.
// ---------------------------------------------------------------------------

typedef short bf16x8 __attribute__((ext_vector_type(8)));
typedef short short8v __attribute__((ext_vector_type(8)));
typedef float f32x16 __attribute__((ext_vector_type(16)));

// workspace layout (bytes)
#define WS_STYLE 0            // [8][512] f32
#define WS_DEMOD 16384        // [8][512] f32
#define WS_WSQ   32768        // [512][512] f32
#define WS_WPACK 1081344      // [144][512][4][8] bf16 (4718592 B)
#define WS_XM    5799936      // [8][66][66][512] bf16 (35684352 B)

__device__ __forceinline__ short f2bf(float f) {
  unsigned u = __float_as_uint(f);
  u += 0x7FFFu + ((u >> 16) & 1u);   // round-to-nearest-even
  return (short)(u >> 16);
}

// ---------------- style_std[b][i] = (sb[b]*0.0625) @ aw[i] + ab[i] + 1 ------
__global__ void k_style(const float* __restrict__ sb, const float* __restrict__ aw,
                        const float* __restrict__ ab, float* __restrict__ style) {
  __shared__ float s_sb[512];
  int b = blockIdx.x;
  for (int i = threadIdx.x; i < 512; i += 256) s_sb[i] = sb[b * 512 + i] * 0.0625f;
  __syncthreads();
  for (int i = threadIdx.x; i < 512; i += 256) {
    const float4* wrow = (const float4*)(aw + (size_t)i * 512);
    float acc = 0.f;
    #pragma unroll 4
    for (int s4 = 0; s4 < 128; ++s4) {
      float4 w4 = wrow[s4];
      float4 sv = *(const float4*)(s_sb + s4 * 4);
      acc += w4.x * sv.x + w4.y * sv.y + w4.z * sv.z + w4.w * sv.w;
    }
    style[b * 512 + i] = acc + ab[i] + 1.0f;
  }
}

// ---------------- wsq[o][i] = sum_tap conv_w^2 ------------------------------
__global__ void k_wsq(const float* __restrict__ cw, float* __restrict__ wsq) {
  int idx = blockIdx.x * 256 + threadIdx.x;   // o*512+i
  const float* p = cw + (size_t)idx * 9;
  float s = 0.f;
  #pragma unroll
  for (int j = 0; j < 9; ++j) s += p[j] * p[j];
  wsq[idx] = s;
}

// ---------------- demod[b][o] = rsqrt(sum_i wsq[o][i]*style^2 + eps) --------
__global__ void k_demod(const float* __restrict__ wsq, const float* __restrict__ style,
                        float* __restrict__ demod) {
  int wid = threadIdx.x >> 6, lane = threadIdx.x & 63;
  int idx = blockIdx.x * 4 + wid;             // (b,o)
  int b = idx >> 9, o = idx & 511;
  const float* wr = wsq + (size_t)o * 512;
  const float* ss = style + b * 512;
  float sum = 0.f;
  #pragma unroll
  for (int k = 0; k < 8; ++k) {
    int i = k * 64 + lane;
    float s = ss[i];
    sum += wr[i] * s * s;
  }
  #pragma unroll
  for (int off = 32; off; off >>= 1) sum += __shfl_down(sum, off);
  if (lane == 0) demod[b * 512 + o] = rsqrtf(sum + 1e-8f);
}

// ---------------- upsample 2x bilinear (half-pixel) + modulate, NHWC pad ----
// xm[b][hp][wp][c], hp/wp in [0,66), border = 0
__global__ void k_upsample(const float* __restrict__ x, const float* __restrict__ style,
                           short* __restrict__ xm) {
  int b = blockIdx.x / 66, hp = blockIdx.x % 66;
  short* xmp = xm + ((size_t)b * 66 + hp) * 66 * 512;
  if (hp == 0 || hp == 65) {
    short8v z = {0, 0, 0, 0, 0, 0, 0, 0};
    for (int u = threadIdx.x; u < 66 * 512 / 8; u += 256) ((short8v*)xmp)[u] = z;
    return;
  }
  int h = hp - 1;
  int j0 = (h >> 1) - 1 + (h & 1);
  float fj = (h & 1) ? 0.25f : 0.75f;
  int j0c = j0 < 0 ? 0 : j0;
  int j1c = j0 + 1 > 31 ? 31 : j0 + 1;
  __shared__ float xt[2][64][33];
  int ccc = threadIdx.x & 63;
  int wsub = threadIdx.x >> 6;
  for (int c0 = 0; c0 < 512; c0 += 64) {
    __syncthreads();
    #pragma unroll 4
    for (int k = 0; k < 16; ++k) {
      int idx = k * 256 + threadIdx.x;
      int ii = idx & 31, cc = (idx >> 5) & 63, jj = idx >> 11;
      xt[jj][cc][ii] = x[(((size_t)b * 512 + c0 + cc) * 32 + (jj ? j1c : j0c)) * 32 + ii];
    }
    __syncthreads();
    float sstyle = style[b * 512 + c0 + ccc];
    #pragma unroll 4
    for (int wk = 0; wk < 16; ++wk) {
      int w = wk * 4 + wsub;
      int i0 = (w >> 1) - 1 + (w & 1);
      float fi = (w & 1) ? 0.25f : 0.75f;
      int i0c = i0 < 0 ? 0 : i0;
      int i1c = i0 + 1 > 31 ? 31 : i0 + 1;
      float v0 = xt[0][ccc][i0c] * (1.f - fi) + xt[0][ccc][i1c] * fi;
      float v1 = xt[1][ccc][i0c] * (1.f - fi) + xt[1][ccc][i1c] * fi;
      float v = (v0 * (1.f - fj) + v1 * fj) * sstyle;
      xmp[(size_t)(w + 1) * 512 + c0 + ccc] = f2bf(v);
    }
    if (wsub == 0) {       // zero side pads for this channel chunk
      xmp[c0 + ccc] = 0;
      xmp[(size_t)65 * 512 + c0 + ccc] = 0;
    }
  }
}

// ---------------- weight pack: wpk[s][o][kg][j] = w[o][i][tap] bf16 ---------
// s = tap*16 + cc ; i = cc*32 + kg*8 + j ; tap = kh*3+kw
__global__ void k_packw(const float* __restrict__ cw, short* __restrict__ wpk) {
  int unit = blockIdx.x * 256 + threadIdx.x;  // < 294912
  int s = unit >> 11;
  int rem = unit & 2047;
  int n = rem >> 2, kg = rem & 3;
  int tap = s >> 4, cc = s & 15;
  int i0 = cc * 32 + kg * 8;
  const float* src = cw + ((size_t)n * 512 + i0) * 9 + tap;
  short8v v;
  #pragma unroll
  for (int j = 0; j < 8; ++j) v[j] = f2bf(src[j * 9]);
  *(short8v*)(wpk + (size_t)unit * 8) = v;
}

// ---------------- main: implicit-GEMM 3x3 conv + fused epilogue -------------
// block: 256 thr = 4 waves (wo in {0,1} x wsrow in {0,1})
// tile: 128 cout x (2 rows x 64 w);  grid = 8b x 32hp x 4nt = 1024
__global__ __launch_bounds__(256) void k_conv(
    const short* __restrict__ xm, const short* __restrict__ wpk,
    const float* __restrict__ demod, const float* __restrict__ convb,
    const float* __restrict__ nscal, const float* __restrict__ noise,
    const float* __restrict__ t, const float* __restrict__ prelu_a,
    float* __restrict__ y) {
  __shared__ short8v A_buf[1056];             // [4 r6][66 wp][4 slot] x 16B
  short* A_lds = (short*)A_buf;
  int tid = threadIdx.x;
  int bid = blockIdx.x;
  int nt = bid & 3, hp = (bid >> 2) & 31, b = bid >> 7;
  int wid = tid >> 6, lane = tid & 63;
  int wo = wid >> 1, wsrow = wid & 1;
  int h = hp * 2 + wsrow;
  int o_base = nt * 128 + wo * 64;
  int l31 = lane & 31, lg = lane >> 5;

  f32x16 zf = {0,0,0,0,0,0,0,0,0,0,0,0,0,0,0,0};
  f32x16 acc[2][2];
  acc[0][0] = zf; acc[0][1] = zf; acc[1][0] = zf; acc[1][1] = zf;

  const short* xb = xm + ((size_t)b * 66 + (size_t)hp * 2) * 66 * 512;

  #pragma unroll 1
  for (int cc = 0; cc < 16; ++cc) {
    __syncthreads();
    // stage xm chunk: 4 rows x 66 wp x 32 ch, slot-swizzled (kg ^= wp&3)
    #pragma unroll
    for (int r = 0; r < 5; ++r) {
      int u = r * 256 + tid;
      if (u < 1056) {
        int r6 = u / 264;
        int rem = u - r6 * 264;
        int wpp = rem >> 2, sp = rem & 3;
        int cofs = cc * 32 + 8 * (sp ^ (wpp & 3));
        short8v v = *(const short8v*)(xb + (size_t)(r6 * 66 + wpp) * 512 + cofs);
        *(short8v*)(A_lds + u * 8) = v;
      }
    }
    __syncthreads();
    #pragma unroll
    for (int tap = 0; tap < 9; ++tap) {
      const int kh = tap / 3, kw = tap % 3;
      const short* wsrc = wpk + (size_t)(tap * 16 + cc) * 512 * 32;
      #pragma unroll
      for (int hf = 0; hf < 2; ++hf) {
        int kg = 2 * hf + lg;
        bf16x8 wf0 = *(const bf16x8*)(wsrc + (o_base + l31) * 32 + kg * 8);
        bf16x8 wf1 = *(const bf16x8*)(wsrc + (o_base + 32 + l31) * 32 + kg * 8);
        int r6 = wsrow + kh;
        int wp0 = l31 + kw;
        int wp1 = 32 + l31 + kw;
        bf16x8 xf0 = *(const bf16x8*)(A_lds + ((r6 * 66 + wp0) * 4 + (kg ^ (wp0 & 3))) * 8);
        bf16x8 xf1 = *(const bf16x8*)(A_lds + ((r6 * 66 + wp1) * 4 + (kg ^ (wp1 & 3))) * 8);
        acc[0][0] = __builtin_amdgcn_mfma_f32_32x32x16_bf16(wf0, xf0, acc[0][0], 0, 0, 0);
        acc[0][1] = __builtin_amdgcn_mfma_f32_32x32x16_bf16(wf0, xf1, acc[0][1], 0, 0, 0);
        acc[1][0] = __builtin_amdgcn_mfma_f32_32x32x16_bf16(wf1, xf0, acc[1][0], 0, 0, 0);
        acc[1][1] = __builtin_amdgcn_mfma_f32_32x32x16_bf16(wf1, xf1, acc[1][1], 0, 0, 0);
      }
    }
  }

  // epilogue: demod + bias + noise + prelu + (y+t)/sqrt2
  float pa = prelu_a[0];
  const float inv_r2 = 1.0f / 1.41421f;
  #pragma unroll
  for (int of = 0; of < 2; ++of) {
    #pragma unroll
    for (int reg = 0; reg < 16; ++reg) {
      int orow = (reg & 3) + 8 * (reg >> 2) + 4 * lg;
      int o = o_base + of * 32 + orow;
      float dm = demod[b * 512 + o];
      float cb = convb[o];
      float ns = nscal[o];
      #pragma unroll
      for (int nf = 0; nf < 2; ++nf) {
        int w = nf * 32 + l31;
        float v = acc[of][nf][reg];
        v = v * dm + cb + ns * noise[((size_t)b * 64 + h) * 64 + w];
        v = (v >= 0.f) ? v : pa * v;
        size_t oi = (((size_t)b * 512 + o) * 64 + h) * 64 + w;
        v = (v + t[oi]) * inv_r2;
        y[oi] = v;
      }
    }
  }
}

// ---------------- toRGB: 1x1 conv over 512 ch + clamp -----------------------
__global__ void k_rgb(const float* __restrict__ y, const float* __restrict__ ow,
                      const float* __restrict__ ob, float* __restrict__ out) {
  int b = blockIdx.x >> 6, h = blockIdx.x & 63;
  int w = threadIdx.x & 63, g = threadIdx.x >> 6;
  const float* yb = y + (((size_t)b * 512) * 64 + h) * 64 + w;
  float s0 = 0.f, s1 = 0.f, s2 = 0.f;
  for (int o = g * 128; o < g * 128 + 128; ++o) {
    float v = yb[(size_t)o * 4096];
    s0 += v * ow[o];
    s1 += v * ow[512 + o];
    s2 += v * ow[1024 + o];
  }
  __shared__ float red[3][4][64];
  red[0][g][w] = s0; red[1][g][w] = s1; red[2][g][w] = s2;
  __syncthreads();
  if (threadIdx.x < 192) {
    int c = threadIdx.x >> 6, ww = threadIdx.x & 63;
    float s = red[c][0][ww] + red[c][1][ww] + red[c][2][ww] + red[c][3][ww];
    s = s * 0.0625f + ob[c];
    s = fminf(fmaxf(s, 0.f), 1.f);
    out[(((size_t)b * 3 + c) * 64 + h) * 64 + ww] = s;
  }
}

extern "C" void kernel_launch(void* const* d_in, const int* in_sizes, int n_in,
                              void* d_out, int out_size, void* d_ws, size_t ws_size,
                              hipStream_t stream) {
  const float* x     = (const float*)d_in[0];
  const float* sb    = (const float*)d_in[1];
  const float* noise = (const float*)d_in[2];
  const float* t     = (const float*)d_in[3];
  const float* aw    = (const float*)d_in[4];
  const float* ab    = (const float*)d_in[5];
  const float* cw    = (const float*)d_in[6];
  const float* cb    = (const float*)d_in[7];
  const float* pa    = (const float*)d_in[8];
  const float* ns    = (const float*)d_in[9];
  const float* ow    = (const float*)d_in[10];
  const float* ob    = (const float*)d_in[11];
  char* ws = (char*)d_ws;
  float* style = (float*)(ws + WS_STYLE);
  float* demod = (float*)(ws + WS_DEMOD);
  float* wsq   = (float*)(ws + WS_WSQ);
  short* wpk   = (short*)(ws + WS_WPACK);
  short* xm    = (short*)(ws + WS_XM);
  float* y   = (float*)d_out;
  float* out = y + 16777216;

  k_style<<<8, 256, 0, stream>>>(sb, aw, ab, style);
  k_wsq<<<1024, 256, 0, stream>>>(cw, wsq);
  k_demod<<<1024, 256, 0, stream>>>(wsq, style, demod);
  k_upsample<<<528, 256, 0, stream>>>(x, style, xm);
  k_packw<<<1152, 256, 0, stream>>>(cw, wpk);
  k_conv<<<1024, 256, 0, stream>>>(xm, wpk, demod, cb, ns, noise, t, pa, y);
  k_rgb<<<512, 256, 0, stream>>>(y, ow, ob, out);
}

// Round 2
// 269.937 us; speedup vs baseline: 1.0988x; 1.0988x over previous
//
#include <hip/hip_runtime.h>

// ---------------------------------------------------------------------------
// ModulatedConvBlock on MI355X (gfx950) — round 2
//   y   = prelu(conv3x3(upsample2x(x)*style, w)*demod + b + ns*noise); y=(y+t)/r2
//   out = clamp(conv1x1(y*OUT_SCALE, ow) + ob, 0, 1)
// Conv = bf16 MFMA implicit GEMM, 1 block/CU, 8 waves, 256cout x (4row x 64w),
// per-(cc,tap) double-buffered LDS weight staging via global_load_lds(16B),
// xm LDS double-buffered across cc with XOR bank swizzle pre-baked in the
// global source address. All MFMA operands come from LDS.
// ---------------------------------------------------------------------------

typedef short bf16x8 __attribute__((ext_vector_type(8)));
typedef short short8v __attribute__((ext_vector_type(8)));
typedef float f32x16 __attribute__((ext_vector_type(16)));

// workspace layout (bytes)
#define WS_STYLE 0            // [8][512] f32
#define WS_DEMOD 16384        // [8][512] f32
#define WS_WSQ   32768        // [512][512] f32
#define WS_WPACK 1081344      // [tap9][cc16][o512][slot4][8] bf16 (4718592 B)
#define WS_XM    5799936      // [8][66][66][512] bf16 (35684352 B)

__device__ __forceinline__ short f2bf(float f) {
  unsigned u = __float_as_uint(f);
  u += 0x7FFFu + ((u >> 16) & 1u);   // round-to-nearest-even
  return (short)(u >> 16);
}

__device__ __forceinline__ void gld16(const short* g, char* l) {
  __builtin_amdgcn_global_load_lds((const __attribute__((address_space(1))) void*)g,
                                   (__attribute__((address_space(3))) void*)l,
                                   16, 0, 0);
}

// ---------------- style_std[b][i] = (sb[b]*0.0625) @ aw[i] + ab[i] + 1 ------
__global__ void k_style(const float* __restrict__ sb, const float* __restrict__ aw,
                        const float* __restrict__ ab, float* __restrict__ style) {
  __shared__ float s_sb[512];
  int b = blockIdx.x;
  for (int i = threadIdx.x; i < 512; i += 256) s_sb[i] = sb[b * 512 + i] * 0.0625f;
  __syncthreads();
  for (int i = threadIdx.x; i < 512; i += 256) {
    const float4* wrow = (const float4*)(aw + (size_t)i * 512);
    float acc = 0.f;
    #pragma unroll 4
    for (int s4 = 0; s4 < 128; ++s4) {
      float4 w4 = wrow[s4];
      float4 sv = *(const float4*)(s_sb + s4 * 4);
      acc += w4.x * sv.x + w4.y * sv.y + w4.z * sv.z + w4.w * sv.w;
    }
    style[b * 512 + i] = acc + ab[i] + 1.0f;
  }
}

// ---------------- wsq[o][i] = sum_tap conv_w^2 ------------------------------
__global__ void k_wsq(const float* __restrict__ cw, float* __restrict__ wsq) {
  int idx = blockIdx.x * 256 + threadIdx.x;   // o*512+i
  const float* p = cw + (size_t)idx * 9;
  float s = 0.f;
  #pragma unroll
  for (int j = 0; j < 9; ++j) s += p[j] * p[j];
  wsq[idx] = s;
}

// ---------------- demod[b][o] = rsqrt(sum_i wsq[o][i]*style^2 + eps) --------
__global__ void k_demod(const float* __restrict__ wsq, const float* __restrict__ style,
                        float* __restrict__ demod) {
  int wid = threadIdx.x >> 6, lane = threadIdx.x & 63;
  int idx = blockIdx.x * 4 + wid;             // (b,o)
  int b = idx >> 9, o = idx & 511;
  const float* wr = wsq + (size_t)o * 512;
  const float* ss = style + b * 512;
  float sum = 0.f;
  #pragma unroll
  for (int k = 0; k < 8; ++k) {
    int i = k * 64 + lane;
    float s = ss[i];
    sum += wr[i] * s * s;
  }
  #pragma unroll
  for (int off = 32; off; off >>= 1) sum += __shfl_down(sum, off);
  if (lane == 0) demod[b * 512 + o] = rsqrtf(sum + 1e-8f);
}

// ---------------- upsample 2x bilinear (half-pixel) + modulate, NHWC pad ----
__global__ void k_upsample(const float* __restrict__ x, const float* __restrict__ style,
                           short* __restrict__ xm) {
  int b = blockIdx.x / 66, hp = blockIdx.x % 66;
  short* xmp = xm + ((size_t)b * 66 + hp) * 66 * 512;
  if (hp == 0 || hp == 65) {
    short8v z = {0, 0, 0, 0, 0, 0, 0, 0};
    for (int u = threadIdx.x; u < 66 * 512 / 8; u += 256) ((short8v*)xmp)[u] = z;
    return;
  }
  int h = hp - 1;
  int j0 = (h >> 1) - 1 + (h & 1);
  float fj = (h & 1) ? 0.25f : 0.75f;
  int j0c = j0 < 0 ? 0 : j0;
  int j1c = j0 + 1 > 31 ? 31 : j0 + 1;
  __shared__ float xt[2][64][33];
  int ccc = threadIdx.x & 63;
  int wsub = threadIdx.x >> 6;
  for (int c0 = 0; c0 < 512; c0 += 64) {
    __syncthreads();
    #pragma unroll 4
    for (int k = 0; k < 16; ++k) {
      int idx = k * 256 + threadIdx.x;
      int ii = idx & 31, cc = (idx >> 5) & 63, jj = idx >> 11;
      xt[jj][cc][ii] = x[(((size_t)b * 512 + c0 + cc) * 32 + (jj ? j1c : j0c)) * 32 + ii];
    }
    __syncthreads();
    float sstyle = style[b * 512 + c0 + ccc];
    #pragma unroll 4
    for (int wk = 0; wk < 16; ++wk) {
      int w = wk * 4 + wsub;
      int i0 = (w >> 1) - 1 + (w & 1);
      float fi = (w & 1) ? 0.25f : 0.75f;
      int i0c = i0 < 0 ? 0 : i0;
      int i1c = i0 + 1 > 31 ? 31 : i0 + 1;
      float v0 = xt[0][ccc][i0c] * (1.f - fi) + xt[0][ccc][i1c] * fi;
      float v1 = xt[1][ccc][i0c] * (1.f - fi) + xt[1][ccc][i1c] * fi;
      float v = (v0 * (1.f - fj) + v1 * fj) * sstyle;
      xmp[(size_t)(w + 1) * 512 + c0 + ccc] = f2bf(v);
    }
    if (wsub == 0) {
      xmp[c0 + ccc] = 0;
      xmp[(size_t)65 * 512 + c0 + ccc] = 0;
    }
  }
}

// ---------------- weight pack with bank pre-swizzle -------------------------
// wpk[tap][cc][o][sp][j] = w[o][ cc*32 + ((sp^(o&3))*8 + j ][tap]
__global__ void k_packw(const float* __restrict__ cw, short* __restrict__ wpk) {
  int unit = blockIdx.x * 256 + threadIdx.x;  // < 294912
  int s = unit >> 11;                          // tap*16+cc
  int rem = unit & 2047;
  int o = rem >> 2, sp = rem & 3;
  int tap = s >> 4, cc = s & 15;
  int i0 = cc * 32 + ((sp ^ (o & 3)) << 3);
  const float* src = cw + ((size_t)o * 512 + i0) * 9 + tap;
  short8v v;
  #pragma unroll
  for (int j = 0; j < 8; ++j) v[j] = f2bf(src[j * 9]);
  *(short8v*)(wpk + (size_t)unit * 8) = v;
}

// ---------------- main conv: 1 block/CU, 8 waves, LDS-staged A and B --------
// grid 256 = 2nt x 16hq x 8b ; block 512 thr
// wave (wo in {0,1}, wsrow in {0..3}): 128 cout x row(hq*4+wsrow) x 64 w
__global__ __launch_bounds__(512, 2) void k_conv(
    const short* __restrict__ xm, const short* __restrict__ wpk,
    const float* __restrict__ demod, const float* __restrict__ convb,
    const float* __restrict__ nscal, const float* __restrict__ noise,
    const float* __restrict__ t, const float* __restrict__ prelu_a,
    float* __restrict__ y) {
  __shared__ char XMs[2][25344];   // [6 r][66 wp][4 slot]x16B per buffer
  __shared__ char WTs[2][16384];   // [256 o][4 slot]x16B per buffer

  int tid = threadIdx.x;
  int bid = blockIdx.x;
  int nt = bid & 1, sp_t = bid >> 1;
  int b = sp_t >> 4, hq = sp_t & 15;
  int wid = tid >> 6, lane = tid & 63;
  int wo = wid & 1, wsrow = wid >> 1;
  int l31 = lane & 31, lg = lane >> 5;

  const short* xb = xm + ((size_t)b * 66 + hq * 4) * 66 * 512;
  int wb0 = ((wo * 128 + l31) << 6) + ((lg ^ (l31 & 3)) << 4);

  // ---- prologue: stage XM (cc=0, 1584 units) + WT (tap0,cc0) ----
  #pragma unroll
  for (int k = 0; k < 3; ++k) {
    int u = k * 512 + tid;
    int r = u / 264, rem = u - r * 264;
    int wp = rem >> 2, spp = rem & 3;
    gld16(xb + (size_t)(r * 66 + wp) * 512 + ((spp ^ (wp & 3)) << 3), XMs[0] + u * 16);
  }
  if (tid < 48) {
    int u = 1536 + tid;
    int rem = u - 1320;           // r = 5
    int wp = rem >> 2, spp = rem & 3;
    gld16(xb + (size_t)(5 * 66 + wp) * 512 + ((spp ^ (wp & 3)) << 3), XMs[0] + u * 16);
  }
  {
    const short* wsrc = wpk + (size_t)(nt * 256) * 32;
    gld16(wsrc + tid * 8, WTs[0] + tid * 16);
    gld16(wsrc + (512 + tid) * 8, WTs[0] + (512 + tid) * 16);
  }

  f32x16 zf = {0,0,0,0,0,0,0,0,0,0,0,0,0,0,0,0};
  f32x16 acc[4][2];
  #pragma unroll
  for (int i = 0; i < 4; ++i) { acc[i][0] = zf; acc[i][1] = zf; }

  __syncthreads();

  #pragma unroll 1
  for (int cc = 0; cc < 16; ++cc) {
    const char* XMc = XMs[cc & 1];
    char* XMn = XMs[(cc & 1) ^ 1];
    int pw = cc & 1;
    #pragma unroll
    for (int tap = 0; tap < 9; ++tap) {
      const int kh = tap / 3, kw = tap % 3;
      const char* WTc = WTs[(pw + tap) & 1];
      char* WTn = (char*)WTs[(pw + tap + 1) & 1];

      // issue next-phase weight stage (consumed after this phase's barrier)
      if (!(cc == 15 && tap == 8)) {
        int ntap = (tap < 8) ? (tap + 1) : 0;
        int ncc  = (tap < 8) ? cc : (cc + 1);
        const short* wsrc = wpk + ((size_t)((ntap * 16 + ncc) * 512) + nt * 256) * 32;
        gld16(wsrc + tid * 8, WTn + tid * 16);
        gld16(wsrc + (512 + tid) * 8, WTn + (512 + tid) * 16);
      }
      // spread next-cc xm staging: one row per tap-phase (taps 3..8)
      if (tap >= 3 && cc < 15) {
        const int r = tap - 3;
        if (tid < 264) {
          int wp = tid >> 2, spp = tid & 3;
          gld16(xb + (size_t)(r * 66 + wp) * 512 + (cc + 1) * 32 + ((spp ^ (wp & 3)) << 3),
                XMn + (r * 264 + tid) * 16);
        }
      }

      // compute phase: 12 ds_read_b128 + 16 MFMA
      int a = l31 + kw;
      int xo = ((wsrow + kh) * 66 + a) * 64 + ((lg ^ (a & 3)) << 4);
      bf16x8 xf00 = *(const bf16x8*)(XMc + xo);
      bf16x8 xf01 = *(const bf16x8*)(XMc + xo + 2048);
      bf16x8 xf10 = *(const bf16x8*)(XMc + (xo ^ 32));
      bf16x8 xf11 = *(const bf16x8*)(XMc + ((xo ^ 32) + 2048));
      bf16x8 wf00 = *(const bf16x8*)(WTc + wb0);
      bf16x8 wf01 = *(const bf16x8*)(WTc + wb0 + 2048);
      bf16x8 wf02 = *(const bf16x8*)(WTc + wb0 + 4096);
      bf16x8 wf03 = *(const bf16x8*)(WTc + wb0 + 6144);
      bf16x8 wf10 = *(const bf16x8*)(WTc + (wb0 ^ 32));
      bf16x8 wf11 = *(const bf16x8*)(WTc + ((wb0 ^ 32) + 2048));
      bf16x8 wf12 = *(const bf16x8*)(WTc + ((wb0 ^ 32) + 4096));
      bf16x8 wf13 = *(const bf16x8*)(WTc + ((wb0 ^ 32) + 6144));

      acc[0][0] = __builtin_amdgcn_mfma_f32_32x32x16_bf16(wf00, xf00, acc[0][0], 0, 0, 0);
      acc[0][1] = __builtin_amdgcn_mfma_f32_32x32x16_bf16(wf00, xf01, acc[0][1], 0, 0, 0);
      acc[1][0] = __builtin_amdgcn_mfma_f32_32x32x16_bf16(wf01, xf00, acc[1][0], 0, 0, 0);
      acc[1][1] = __builtin_amdgcn_mfma_f32_32x32x16_bf16(wf01, xf01, acc[1][1], 0, 0, 0);
      acc[2][0] = __builtin_amdgcn_mfma_f32_32x32x16_bf16(wf02, xf00, acc[2][0], 0, 0, 0);
      acc[2][1] = __builtin_amdgcn_mfma_f32_32x32x16_bf16(wf02, xf01, acc[2][1], 0, 0, 0);
      acc[3][0] = __builtin_amdgcn_mfma_f32_32x32x16_bf16(wf03, xf00, acc[3][0], 0, 0, 0);
      acc[3][1] = __builtin_amdgcn_mfma_f32_32x32x16_bf16(wf03, xf01, acc[3][1], 0, 0, 0);
      acc[0][0] = __builtin_amdgcn_mfma_f32_32x32x16_bf16(wf10, xf10, acc[0][0], 0, 0, 0);
      acc[0][1] = __builtin_amdgcn_mfma_f32_32x32x16_bf16(wf10, xf11, acc[0][1], 0, 0, 0);
      acc[1][0] = __builtin_amdgcn_mfma_f32_32x32x16_bf16(wf11, xf10, acc[1][0], 0, 0, 0);
      acc[1][1] = __builtin_amdgcn_mfma_f32_32x32x16_bf16(wf11, xf11, acc[1][1], 0, 0, 0);
      acc[2][0] = __builtin_amdgcn_mfma_f32_32x32x16_bf16(wf12, xf10, acc[2][0], 0, 0, 0);
      acc[2][1] = __builtin_amdgcn_mfma_f32_32x32x16_bf16(wf12, xf11, acc[2][1], 0, 0, 0);
      acc[3][0] = __builtin_amdgcn_mfma_f32_32x32x16_bf16(wf13, xf10, acc[3][0], 0, 0, 0);
      acc[3][1] = __builtin_amdgcn_mfma_f32_32x32x16_bf16(wf13, xf11, acc[3][1], 0, 0, 0);

      __syncthreads();
    }
  }

  // ---- epilogue: demod + bias + noise + prelu + (y+t)/sqrt2 ----
  float pa = prelu_a[0];
  const float inv_r2 = 1.0f / 1.41421f;
  int h = hq * 4 + wsrow;
  float nz0 = noise[((size_t)b * 64 + h) * 64 + l31];
  float nz1 = noise[((size_t)b * 64 + h) * 64 + 32 + l31];
  #pragma unroll
  for (int cf = 0; cf < 4; ++cf) {
    #pragma unroll
    for (int reg = 0; reg < 16; ++reg) {
      int orow = (reg & 3) + 8 * (reg >> 2) + 4 * lg;
      int o = nt * 256 + wo * 128 + cf * 32 + orow;
      float dm = demod[b * 512 + o];
      float cb = convb[o];
      float ns = nscal[o];
      #pragma unroll
      for (int nf = 0; nf < 2; ++nf) {
        int w = nf * 32 + l31;
        float v = acc[cf][nf][reg];
        v = v * dm + cb + ns * (nf ? nz1 : nz0);
        v = (v >= 0.f) ? v : pa * v;
        size_t oi = (((size_t)b * 512 + o) * 64 + h) * 64 + w;
        v = (v + t[oi]) * inv_r2;
        y[oi] = v;
      }
    }
  }
}

// ---------------- toRGB: 1x1 conv over 512 ch + clamp -----------------------
__global__ void k_rgb(const float* __restrict__ y, const float* __restrict__ ow,
                      const float* __restrict__ ob, float* __restrict__ out) {
  int b = blockIdx.x >> 6, h = blockIdx.x & 63;
  int w = threadIdx.x & 63, g = threadIdx.x >> 6;
  const float* yb = y + (((size_t)b * 512) * 64 + h) * 64 + w;
  float s0 = 0.f, s1 = 0.f, s2 = 0.f;
  for (int o = g * 128; o < g * 128 + 128; ++o) {
    float v = yb[(size_t)o * 4096];
    s0 += v * ow[o];
    s1 += v * ow[512 + o];
    s2 += v * ow[1024 + o];
  }
  __shared__ float red[3][4][64];
  red[0][g][w] = s0; red[1][g][w] = s1; red[2][g][w] = s2;
  __syncthreads();
  if (threadIdx.x < 192) {
    int c = threadIdx.x >> 6, ww = threadIdx.x & 63;
    float s = red[c][0][ww] + red[c][1][ww] + red[c][2][ww] + red[c][3][ww];
    s = s * 0.0625f + ob[c];
    s = fminf(fmaxf(s, 0.f), 1.f);
    out[(((size_t)b * 3 + c) * 64 + h) * 64 + ww] = s;
  }
}

extern "C" void kernel_launch(void* const* d_in, const int* in_sizes, int n_in,
                              void* d_out, int out_size, void* d_ws, size_t ws_size,
                              hipStream_t stream) {
  const float* x     = (const float*)d_in[0];
  const float* sb    = (const float*)d_in[1];
  const float* noise = (const float*)d_in[2];
  const float* t     = (const float*)d_in[3];
  const float* aw    = (const float*)d_in[4];
  const float* ab    = (const float*)d_in[5];
  const float* cw    = (const float*)d_in[6];
  const float* cb    = (const float*)d_in[7];
  const float* pa    = (const float*)d_in[8];
  const float* ns    = (const float*)d_in[9];
  const float* ow    = (const float*)d_in[10];
  const float* ob    = (const float*)d_in[11];
  char* ws = (char*)d_ws;
  float* style = (float*)(ws + WS_STYLE);
  float* demod = (float*)(ws + WS_DEMOD);
  float* wsq   = (float*)(ws + WS_WSQ);
  short* wpk   = (short*)(ws + WS_WPACK);
  short* xm    = (short*)(ws + WS_XM);
  float* y   = (float*)d_out;
  float* out = y + 16777216;

  k_style<<<8, 256, 0, stream>>>(sb, aw, ab, style);
  k_wsq<<<1024, 256, 0, stream>>>(cw, wsq);
  k_demod<<<1024, 256, 0, stream>>>(wsq, style, demod);
  k_upsample<<<528, 256, 0, stream>>>(x, style, xm);
  k_packw<<<1152, 256, 0, stream>>>(cw, wpk);
  k_conv<<<256, 512, 0, stream>>>(xm, wpk, demod, cb, ns, noise, t, pa, y);
  k_rgb<<<512, 256, 0, stream>>>(y, ow, ob, out);
}

// Round 3
// 254.192 us; speedup vs baseline: 1.1668x; 1.0619x over previous
//
#include <hip/hip_runtime.h>

// ---------------------------------------------------------------------------
// ModulatedConvBlock on MI355X (gfx950) — round 3
// Conv = bf16 MFMA implicit GEMM. 2 blocks/CU (4 waves each), per-(cc,tap)
// double-buffered LDS weight staging via global_load_lds(16B), xm LDS
// double-buffered across cc. Bank swizzle keyed on (row>>1)&3 (full 32-bank
// spread for 64B-stride rows), pre-baked into pack/staging source addresses.
// ---------------------------------------------------------------------------

typedef short bf16x8 __attribute__((ext_vector_type(8)));
typedef short short8v __attribute__((ext_vector_type(8)));
typedef float f32x16 __attribute__((ext_vector_type(16)));

// workspace layout (bytes)
#define WS_STYLE 0            // [8][512] f32
#define WS_DEMOD 16384        // [8][512] f32
#define WS_WSQ   32768        // [512][512] f32
#define WS_WPACK 1081344      // [tap9][cc16][o512][slot4][8] bf16 (4718592 B)
#define WS_XM    5799936      // [8][66][66][512] bf16 (35684352 B)

__device__ __forceinline__ short f2bf(float f) {
  unsigned u = __float_as_uint(f);
  u += 0x7FFFu + ((u >> 16) & 1u);   // round-to-nearest-even
  return (short)(u >> 16);
}

__device__ __forceinline__ void gld16(const short* g, char* l) {
  __builtin_amdgcn_global_load_lds((const __attribute__((address_space(1))) void*)g,
                                   (__attribute__((address_space(3))) void*)l,
                                   16, 0, 0);
}

// ---------------- style_std[b][i] = (sb[b]*0.0625) @ aw[i] + ab[i] + 1 ------
__global__ void k_style(const float* __restrict__ sb, const float* __restrict__ aw,
                        const float* __restrict__ ab, float* __restrict__ style) {
  __shared__ float s_sb[512];
  int b = blockIdx.x;
  for (int i = threadIdx.x; i < 512; i += 256) s_sb[i] = sb[b * 512 + i] * 0.0625f;
  __syncthreads();
  for (int i = threadIdx.x; i < 512; i += 256) {
    const float4* wrow = (const float4*)(aw + (size_t)i * 512);
    float acc = 0.f;
    #pragma unroll 4
    for (int s4 = 0; s4 < 128; ++s4) {
      float4 w4 = wrow[s4];
      float4 sv = *(const float4*)(s_sb + s4 * 4);
      acc += w4.x * sv.x + w4.y * sv.y + w4.z * sv.z + w4.w * sv.w;
    }
    style[b * 512 + i] = acc + ab[i] + 1.0f;
  }
}

// ---------------- wsq[o][i] = sum_tap conv_w^2 ------------------------------
__global__ void k_wsq(const float* __restrict__ cw, float* __restrict__ wsq) {
  int idx = blockIdx.x * 256 + threadIdx.x;   // o*512+i
  const float* p = cw + (size_t)idx * 9;
  float s = 0.f;
  #pragma unroll
  for (int j = 0; j < 9; ++j) s += p[j] * p[j];
  wsq[idx] = s;
}

// ---------------- demod[b][o] = rsqrt(sum_i wsq[o][i]*style^2 + eps) --------
__global__ void k_demod(const float* __restrict__ wsq, const float* __restrict__ style,
                        float* __restrict__ demod) {
  int wid = threadIdx.x >> 6, lane = threadIdx.x & 63;
  int idx = blockIdx.x * 4 + wid;             // (b,o)
  int b = idx >> 9, o = idx & 511;
  const float* wr = wsq + (size_t)o * 512;
  const float* ss = style + b * 512;
  float sum = 0.f;
  #pragma unroll
  for (int k = 0; k < 8; ++k) {
    int i = k * 64 + lane;
    float s = ss[i];
    sum += wr[i] * s * s;
  }
  #pragma unroll
  for (int off = 32; off; off >>= 1) sum += __shfl_down(sum, off);
  if (lane == 0) demod[b * 512 + o] = rsqrtf(sum + 1e-8f);
}

// ---------------- upsample 2x bilinear (half-pixel) + modulate, NHWC pad ----
__global__ void k_upsample(const float* __restrict__ x, const float* __restrict__ style,
                           short* __restrict__ xm) {
  int b = blockIdx.x / 66, hp = blockIdx.x % 66;
  short* xmp = xm + ((size_t)b * 66 + hp) * 66 * 512;
  if (hp == 0 || hp == 65) {
    short8v z = {0, 0, 0, 0, 0, 0, 0, 0};
    for (int u = threadIdx.x; u < 66 * 512 / 8; u += 256) ((short8v*)xmp)[u] = z;
    return;
  }
  int h = hp - 1;
  int j0 = (h >> 1) - 1 + (h & 1);
  float fj = (h & 1) ? 0.25f : 0.75f;
  int j0c = j0 < 0 ? 0 : j0;
  int j1c = j0 + 1 > 31 ? 31 : j0 + 1;
  __shared__ float xt[2][64][33];
  int ccc = threadIdx.x & 63;
  int wsub = threadIdx.x >> 6;
  for (int c0 = 0; c0 < 512; c0 += 64) {
    __syncthreads();
    #pragma unroll 4
    for (int k = 0; k < 16; ++k) {
      int idx = k * 256 + threadIdx.x;
      int ii = idx & 31, cc = (idx >> 5) & 63, jj = idx >> 11;
      xt[jj][cc][ii] = x[(((size_t)b * 512 + c0 + cc) * 32 + (jj ? j1c : j0c)) * 32 + ii];
    }
    __syncthreads();
    float sstyle = style[b * 512 + c0 + ccc];
    #pragma unroll 4
    for (int wk = 0; wk < 16; ++wk) {
      int w = wk * 4 + wsub;
      int i0 = (w >> 1) - 1 + (w & 1);
      float fi = (w & 1) ? 0.25f : 0.75f;
      int i0c = i0 < 0 ? 0 : i0;
      int i1c = i0 + 1 > 31 ? 31 : i0 + 1;
      float v0 = xt[0][ccc][i0c] * (1.f - fi) + xt[0][ccc][i1c] * fi;
      float v1 = xt[1][ccc][i0c] * (1.f - fi) + xt[1][ccc][i1c] * fi;
      float v = (v0 * (1.f - fj) + v1 * fj) * sstyle;
      xmp[(size_t)(w + 1) * 512 + c0 + ccc] = f2bf(v);
    }
    if (wsub == 0) {
      xmp[c0 + ccc] = 0;
      xmp[(size_t)65 * 512 + c0 + ccc] = 0;
    }
  }
}

// ---------------- weight pack with bank pre-swizzle -------------------------
// wpk[tap][cc][o][sp][j] = w[o][ cc*32 + (sp ^ ((o>>1)&3))*8 + j ][tap]
__global__ void k_packw(const float* __restrict__ cw, short* __restrict__ wpk) {
  int unit = blockIdx.x * 256 + threadIdx.x;  // < 294912
  int s = unit >> 11;                          // tap*16+cc
  int rem = unit & 2047;
  int o = rem >> 2, sp = rem & 3;
  int tap = s >> 4, cc = s & 15;
  int i0 = cc * 32 + ((sp ^ ((o >> 1) & 3)) << 3);
  const float* src = cw + ((size_t)o * 512 + i0) * 9 + tap;
  short8v v;
  #pragma unroll
  for (int j = 0; j < 8; ++j) v[j] = f2bf(src[j * 9]);
  *(short8v*)(wpk + (size_t)unit * 8) = v;
}

// ---------------- main conv: 2 blocks/CU, 4 waves, LDS-staged A and B -------
// grid 512 = 2nt x 32hpair x 8b ; block 256 thr
// wave (wo in {0,1}, wsrow in {0,1}): 128 cout x row(hpair*2+wsrow) x 64 w
__global__ __launch_bounds__(256, 2) void k_conv(
    const short* __restrict__ xm, const short* __restrict__ wpk,
    const float* __restrict__ demod, const float* __restrict__ convb,
    const float* __restrict__ nscal, const float* __restrict__ noise,
    const float* __restrict__ t, const float* __restrict__ prelu_a,
    float* __restrict__ y) {
  __shared__ char XMs[2][16896];   // [4 r][66 wp][4 slot]x16B per buffer
  __shared__ char WTs[2][16384];   // [256 o][4 slot]x16B per buffer

  int tid = threadIdx.x;
  int bid = blockIdx.x;
  int nt = bid & 1, hpair = (bid >> 1) & 31, b = bid >> 6;
  int wid = tid >> 6, lane = tid & 63;
  int wo = wid & 1, wsrow = wid >> 1;
  int l31 = lane & 31, lg = lane >> 5;

  const short* xb = xm + ((size_t)b * 66 + hpair * 2) * 66 * 512;
  int wb0 = ((wo * 128 + l31) << 6) + ((lg ^ ((l31 >> 1) & 3)) << 4);

  // ---- prologue: stage XM (cc=0, 1056 units) + WT (tap0,cc0) ----
  #pragma unroll
  for (int k = 0; k < 4; ++k) {
    int u = k * 256 + tid;
    int r = u / 264, rem = u - r * 264;
    int wp = rem >> 2, spp = rem & 3;
    gld16(xb + (size_t)(r * 66 + wp) * 512 + ((spp ^ ((wp >> 1) & 3)) << 3), XMs[0] + u * 16);
  }
  if (tid < 32) {
    int u = 1024 + tid;
    int rem = u - 792;              // r = 3
    int wp = rem >> 2, spp = rem & 3;
    gld16(xb + (size_t)(3 * 66 + wp) * 512 + ((spp ^ ((wp >> 1) & 3)) << 3), XMs[0] + u * 16);
  }
  #pragma unroll
  for (int k = 0; k < 4; ++k) {
    int u = k * 256 + tid;
    gld16(wpk + (size_t)(nt * 256) * 32 + u * 8, WTs[0] + u * 16);
  }

  f32x16 zf = {0,0,0,0,0,0,0,0,0,0,0,0,0,0,0,0};
  f32x16 acc[4][2];
  #pragma unroll
  for (int i = 0; i < 4; ++i) { acc[i][0] = zf; acc[i][1] = zf; }

  __syncthreads();

  #pragma unroll 1
  for (int cc = 0; cc < 16; ++cc) {
    const char* XMc = XMs[cc & 1];
    char* XMn = XMs[(cc & 1) ^ 1];
    #pragma unroll
    for (int tap = 0; tap < 9; ++tap) {
      const int kh = tap / 3, kw = tap % 3;
      const char* WTc = WTs[(cc + tap) & 1];
      char* WTn = (char*)WTs[(cc + tap + 1) & 1];

      // issue next-phase weight stage (consumed after this phase's barrier)
      if (!(cc == 15 && tap == 8)) {
        int ntap = (tap < 8) ? (tap + 1) : 0;
        int ncc  = (tap < 8) ? cc : (cc + 1);
        const short* wsrc = wpk + ((size_t)((ntap * 16 + ncc) * 512) + nt * 256) * 32;
        #pragma unroll
        for (int k = 0; k < 4; ++k) {
          int u = k * 256 + tid;
          gld16(wsrc + u * 8, WTn + u * 16);
        }
      }
      // spread next-cc xm staging over taps 0..5 (176 units/phase)
      if (tap <= 5 && cc < 15 && tid < 176) {
        int u = tap * 176 + tid;
        int r = u / 264, rem = u - r * 264;
        int wp = rem >> 2, spp = rem & 3;
        gld16(xb + (size_t)(r * 66 + wp) * 512 + (cc + 1) * 32 + ((spp ^ ((wp >> 1) & 3)) << 3),
              XMn + u * 16);
      }

      // compute phase: 12 ds_read_b128 + 16 MFMA
      int a = l31 + kw;
      int xo = ((wsrow + kh) * 66 + a) * 64 + ((lg ^ ((a >> 1) & 3)) << 4);
      bf16x8 xf00 = *(const bf16x8*)(XMc + xo);
      bf16x8 xf01 = *(const bf16x8*)(XMc + xo + 2048);
      bf16x8 xf10 = *(const bf16x8*)(XMc + (xo ^ 32));
      bf16x8 xf11 = *(const bf16x8*)(XMc + ((xo ^ 32) + 2048));
      bf16x8 wf00 = *(const bf16x8*)(WTc + wb0);
      bf16x8 wf01 = *(const bf16x8*)(WTc + wb0 + 2048);
      bf16x8 wf02 = *(const bf16x8*)(WTc + wb0 + 4096);
      bf16x8 wf03 = *(const bf16x8*)(WTc + wb0 + 6144);
      bf16x8 wf10 = *(const bf16x8*)(WTc + (wb0 ^ 32));
      bf16x8 wf11 = *(const bf16x8*)(WTc + ((wb0 ^ 32) + 2048));
      bf16x8 wf12 = *(const bf16x8*)(WTc + ((wb0 ^ 32) + 4096));
      bf16x8 wf13 = *(const bf16x8*)(WTc + ((wb0 ^ 32) + 6144));

      __builtin_amdgcn_s_setprio(1);
      acc[0][0] = __builtin_amdgcn_mfma_f32_32x32x16_bf16(wf00, xf00, acc[0][0], 0, 0, 0);
      acc[0][1] = __builtin_amdgcn_mfma_f32_32x32x16_bf16(wf00, xf01, acc[0][1], 0, 0, 0);
      acc[1][0] = __builtin_amdgcn_mfma_f32_32x32x16_bf16(wf01, xf00, acc[1][0], 0, 0, 0);
      acc[1][1] = __builtin_amdgcn_mfma_f32_32x32x16_bf16(wf01, xf01, acc[1][1], 0, 0, 0);
      acc[2][0] = __builtin_amdgcn_mfma_f32_32x32x16_bf16(wf02, xf00, acc[2][0], 0, 0, 0);
      acc[2][1] = __builtin_amdgcn_mfma_f32_32x32x16_bf16(wf02, xf01, acc[2][1], 0, 0, 0);
      acc[3][0] = __builtin_amdgcn_mfma_f32_32x32x16_bf16(wf03, xf00, acc[3][0], 0, 0, 0);
      acc[3][1] = __builtin_amdgcn_mfma_f32_32x32x16_bf16(wf03, xf01, acc[3][1], 0, 0, 0);
      acc[0][0] = __builtin_amdgcn_mfma_f32_32x32x16_bf16(wf10, xf10, acc[0][0], 0, 0, 0);
      acc[0][1] = __builtin_amdgcn_mfma_f32_32x32x16_bf16(wf10, xf11, acc[0][1], 0, 0, 0);
      acc[1][0] = __builtin_amdgcn_mfma_f32_32x32x16_bf16(wf11, xf10, acc[1][0], 0, 0, 0);
      acc[1][1] = __builtin_amdgcn_mfma_f32_32x32x16_bf16(wf11, xf11, acc[1][1], 0, 0, 0);
      acc[2][0] = __builtin_amdgcn_mfma_f32_32x32x16_bf16(wf12, xf10, acc[2][0], 0, 0, 0);
      acc[2][1] = __builtin_amdgcn_mfma_f32_32x32x16_bf16(wf12, xf11, acc[2][1], 0, 0, 0);
      acc[3][0] = __builtin_amdgcn_mfma_f32_32x32x16_bf16(wf13, xf10, acc[3][0], 0, 0, 0);
      acc[3][1] = __builtin_amdgcn_mfma_f32_32x32x16_bf16(wf13, xf11, acc[3][1], 0, 0, 0);
      __builtin_amdgcn_s_setprio(0);

      __syncthreads();
    }
  }

  // ---- epilogue: demod + bias + noise + prelu + (y+t)/sqrt2 ----
  float pa = prelu_a[0];
  const float inv_r2 = 1.0f / 1.41421f;
  int h = hpair * 2 + wsrow;
  float nz0 = noise[((size_t)b * 64 + h) * 64 + l31];
  float nz1 = noise[((size_t)b * 64 + h) * 64 + 32 + l31];
  #pragma unroll
  for (int cf = 0; cf < 4; ++cf) {
    #pragma unroll
    for (int reg = 0; reg < 16; ++reg) {
      int orow = (reg & 3) + 8 * (reg >> 2) + 4 * lg;
      int o = nt * 256 + wo * 128 + cf * 32 + orow;
      float dm = demod[b * 512 + o];
      float cb = convb[o];
      float ns = nscal[o];
      #pragma unroll
      for (int nf = 0; nf < 2; ++nf) {
        int w = nf * 32 + l31;
        float v = acc[cf][nf][reg];
        v = v * dm + cb + ns * (nf ? nz1 : nz0);
        v = (v >= 0.f) ? v : pa * v;
        size_t oi = (((size_t)b * 512 + o) * 64 + h) * 64 + w;
        v = (v + t[oi]) * inv_r2;
        y[oi] = v;
      }
    }
  }
}

// ---------------- toRGB: 1x1 conv over 512 ch + clamp -----------------------
__global__ void k_rgb(const float* __restrict__ y, const float* __restrict__ ow,
                      const float* __restrict__ ob, float* __restrict__ out) {
  int b = blockIdx.x >> 6, h = blockIdx.x & 63;
  int w = threadIdx.x & 63, g = threadIdx.x >> 6;
  const float* yb = y + (((size_t)b * 512) * 64 + h) * 64 + w;
  float s0 = 0.f, s1 = 0.f, s2 = 0.f;
  for (int o = g * 128; o < g * 128 + 128; ++o) {
    float v = yb[(size_t)o * 4096];
    s0 += v * ow[o];
    s1 += v * ow[512 + o];
    s2 += v * ow[1024 + o];
  }
  __shared__ float red[3][4][64];
  red[0][g][w] = s0; red[1][g][w] = s1; red[2][g][w] = s2;
  __syncthreads();
  if (threadIdx.x < 192) {
    int c = threadIdx.x >> 6, ww = threadIdx.x & 63;
    float s = red[c][0][ww] + red[c][1][ww] + red[c][2][ww] + red[c][3][ww];
    s = s * 0.0625f + ob[c];
    s = fminf(fmaxf(s, 0.f), 1.f);
    out[(((size_t)b * 3 + c) * 64 + h) * 64 + ww] = s;
  }
}

extern "C" void kernel_launch(void* const* d_in, const int* in_sizes, int n_in,
                              void* d_out, int out_size, void* d_ws, size_t ws_size,
                              hipStream_t stream) {
  const float* x     = (const float*)d_in[0];
  const float* sb    = (const float*)d_in[1];
  const float* noise = (const float*)d_in[2];
  const float* t     = (const float*)d_in[3];
  const float* aw    = (const float*)d_in[4];
  const float* ab    = (const float*)d_in[5];
  const float* cw    = (const float*)d_in[6];
  const float* cb    = (const float*)d_in[7];
  const float* pa    = (const float*)d_in[8];
  const float* ns    = (const float*)d_in[9];
  const float* ow    = (const float*)d_in[10];
  const float* ob    = (const float*)d_in[11];
  char* ws = (char*)d_ws;
  float* style = (float*)(ws + WS_STYLE);
  float* demod = (float*)(ws + WS_DEMOD);
  float* wsq   = (float*)(ws + WS_WSQ);
  short* wpk   = (short*)(ws + WS_WPACK);
  short* xm    = (short*)(ws + WS_XM);
  float* y   = (float*)d_out;
  float* out = y + 16777216;

  k_style<<<8, 256, 0, stream>>>(sb, aw, ab, style);
  k_wsq<<<1024, 256, 0, stream>>>(cw, wsq);
  k_demod<<<1024, 256, 0, stream>>>(wsq, style, demod);
  k_upsample<<<528, 256, 0, stream>>>(x, style, xm);
  k_packw<<<1152, 256, 0, stream>>>(cw, wpk);
  k_conv<<<512, 256, 0, stream>>>(xm, wpk, demod, cb, ns, noise, t, pa, y);
  k_rgb<<<512, 256, 0, stream>>>(y, ow, ob, out);
}